// Round 8
// baseline (184.442 us; speedup 1.0000x reference)
//
#include <hip/hip_runtime.h>
#include <math.h>

#define NEDGES 2097152
#define CAPB   9216    /* per-(graph,quarter) bucket cap: mean 8192, sigma~90 -> +11 sigma */
#define CAPQ   9728    /* per-quarter CSR cap: 8192 + align-pad<=768 + 8.5 sigma           */

/* ws layout (bytes) */
#define OFF_GFILL 0u          /* int[256] per-bucket fill                    */
#define OFF_ARR1  1024u       /* int[64]  dis-exchange flags                 */
#define OFF_ARR2  1280u       /* int[64]  h1-exchange flags                  */
#define OFF_ARR3  1536u       /* int[64]  pool/tail flags                    */
#define OFF_POOL4 2048u       /* float[64*4*32] = 32768 -> 34816             */
#define OFF_DIS   34816u      /* float[65536] = 262144 -> 296960             */
#define OFF_H1G   296960u     /* float[65536*32] = 8388608 -> 8685568        */
#define OFF_EBUF  8685568u    /* uint[256*CAPB] = 9437184 -> 18122752        */

__device__ __forceinline__ float ftanh(float x) {
    float e = __expf(2.f * x);
    return 1.f - 2.f * __builtin_amdgcn_rcpf(e + 1.f);
}

/* ---- bucket edges by (graph, dst-quarter): 256 buckets; 1024 threads/block
   (16 waves/CU) for latency hiding. R5/R7-proven code. ---- */
__global__ __launch_bounds__(1024) void k_bucket(
        const int* __restrict__ src, const int* __restrict__ dst,
        int* __restrict__ gfill, unsigned int* __restrict__ ebuf) {
    __shared__ unsigned int sorted[8192];
    __shared__ int hist[256], lexcl[256], gbase[256], lfill[256];
    __shared__ int wsum[4];
    int t = threadIdx.x;
    int blk = blockIdx.x;
    int lane = t & 63, wid = t >> 6;

    if (t < 256) { hist[t] = 0; lfill[t] = 0; }
    __syncthreads();

    unsigned int pk[8];
    {
        const int4* s4p = (const int4*)(src + blk * 8192);
        const int4* d4p = (const int4*)(dst + blk * 8192);
        #pragma unroll
        for (int k = 0; k < 2; k++) {
            int4 s4 = s4p[k * 1024 + t];
            int4 d4 = d4p[k * 1024 + t];
            int ss[4] = { s4.x, s4.y, s4.z, s4.w };
            int dd[4] = { d4.x, d4.y, d4.z, d4.w };
            #pragma unroll
            for (int j = 0; j < 4; j++) {
                int gg = ss[j] >> 10;
                /* pack: src_local | dst_local<<10 | g<<20 ; bucket = pk>>18 */
                pk[k * 4 + j] = (unsigned int)((ss[j] & 1023) | ((dd[j] & 1023) << 10) | (gg << 20));
                atomicAdd(&hist[(gg << 2) | ((dd[j] >> 8) & 3)], 1);
            }
        }
    }
    __syncthreads();

    int hA = 0, xxA = 0;
    if (t < 256) {
        hA = hist[t];
        xxA = hA;
        #pragma unroll
        for (int off = 1; off < 64; off <<= 1) {
            int y = __shfl_up(xxA, off, 64);
            if (lane >= off) xxA += y;
        }
        if (lane == 63) wsum[wid] = xxA;
    }
    __syncthreads();
    if (t < 256) {
        int pre = 0;
        for (int w = 0; w < wid; w++) pre += wsum[w];
        lexcl[t] = pre + xxA - hA;
        gbase[t] = atomicAdd(&gfill[t], hA);
    }
    __syncthreads();

    #pragma unroll
    for (int k = 0; k < 8; k++) {
        int b = pk[k] >> 18;
        int pos = lexcl[b] + atomicAdd(&lfill[b], 1);
        sorted[pos] = pk[k];
    }
    __syncthreads();
    #pragma unroll
    for (int k = 0; k < 8; k++) {
        int i = k * 1024 + t;
        unsigned int p = sorted[i];
        int b = p >> 18;
        ebuf[(size_t)b * CAPB + gbase[b] + (i - lexcl[b])] = p;
    }
}

/* ---- quarter-graph GCN: R1-proven f32 body (58us, absmax 0) + hoisted
   x@W1 matmul (pre-flag-wait) + folded MLP tail. 256 blocks x 1024 thr,
   ~155 KB LDS -> 1 block/CU -> all 256 co-resident -> flag syncs safe. ---- */
__global__ __launch_bounds__(1024, 1) void k_gcn(
        const float* __restrict__ x,
        const float* __restrict__ W1, const float* __restrict__ b1,
        const float* __restrict__ W2, const float* __restrict__ b2,
        const float* __restrict__ Wl, const float* __restrict__ bl,
        const float* __restrict__ Wp, const float* __restrict__ bp,
        const float* __restrict__ Vw1, const float* __restrict__ Vb1,
        const float* __restrict__ Vw2, const float* __restrict__ Vb2,
        const float* __restrict__ Vw3, const float* __restrict__ Vb3,
        const float* __restrict__ Cw1, const float* __restrict__ Cb1,
        const float* __restrict__ Cw2, const float* __restrict__ Cb2,
        const float* __restrict__ share,
        const unsigned int* __restrict__ ebuf, const int* __restrict__ gfill,
        float* __restrict__ disg, float* __restrict__ h1g,
        int* __restrict__ arr1, int* __restrict__ arr2, int* __restrict__ arr3,
        float* __restrict__ pooled4, float* __restrict__ out) {
    __shared__ float hsL[1025 * 32];          /* 131200 B, row 1024 = zeros */
    __shared__ unsigned short lcsr[CAPQ];     /* 19456 B */
    __shared__ int hist[256], lrow[256], lfill[256];
    __shared__ int wsum[4];
    float4* hsL4 = (float4*)hsL;

    int t = threadIdx.x;
    int g = blockIdx.x & 63, part = blockIdx.x >> 6;
    int bkt = (g << 2) | part;
    int cnt = gfill[bkt];
    const unsigned int* eb = ebuf + (size_t)bkt * CAPB;
    int lane = t & 63, wid = t >> 6;

    /* preload x row early; latency overlaps the edge scans */
    float inr[16];
    {
        const float4* in4 = (const float4*)(x + ((size_t)(g << 10) + t) * 16);
        #pragma unroll
        for (int k = 0; k < 4; k++) {
            float4 v = in4[k];
            inr[4*k] = v.x; inr[4*k+1] = v.y; inr[4*k+2] = v.z; inr[4*k+3] = v.w;
        }
    }

    if (t < 256) hist[t] = 0;
    if (t < 32) hsL[1024 * 32 + t] = 0.f;     /* zero row for CSR padding */
    __syncthreads();

    /* pass 1: degree hist over own quarter bucket (~8K edges) */
    for (int i = t; i < cnt; i += 1024) atomicAdd(&hist[(eb[i] >> 10) & 255], 1);
    __syncthreads();

    /* publish this quarter's dis, release flag 1 */
    int dq = 0, r4 = 0;
    if (t < 256) {
        dq = hist[t]; r4 = (dq + 3) & ~3;
        disg[(g << 10) + part * 256 + t] = rsqrtf((float)(dq + 1));
    }
    __syncthreads();  /* drains vmem: disg stores done before release */
    if (t == 0)
        __hip_atomic_fetch_add(arr1 + g, 1, __ATOMIC_RELEASE, __HIP_MEMORY_SCOPE_AGENT);

    /* HOISTED: xw = x @ W1^T (dis scaling deferred past the flag wait).
       Pure VALU work filling the scan/scatter/wait latency window. */
    float xw[32];
    #pragma unroll
    for (int o = 0; o < 32; o++) {
        float s = 0.f;
        #pragma unroll
        for (int k = 0; k < 16; k++) s += inr[k] * W1[o * 16 + k];
        xw[o] = s;
    }

    /* exclusive scan of 4-aligned degrees -> CSR row starts */
    int xx = r4;
    #pragma unroll
    for (int off = 1; off < 64; off <<= 1) {
        int y = __shfl_up(xx, off, 64);
        if (lane >= off) xx += y;
    }
    if (t < 256 && lane == 63) wsum[wid] = xx;
    __syncthreads();
    if (t < 256) {
        int pre = 0;
        for (int w = 0; w < wid; w++) pre += wsum[w];
        lrow[t] = pre + xx - r4;
        lfill[t] = 0;
    }
    __syncthreads();

    /* pass 2: scatter own bucket into LDS CSR; pad rows to x4 */
    for (int i = t; i < cnt; i += 1024) {
        unsigned int v = eb[i];
        int dl = (v >> 10) & 255;
        int pos = lrow[dl] + atomicAdd(&lfill[dl], 1);
        lcsr[pos] = (unsigned short)(v & 1023);
    }
    if (t < 256) {
        int st = lrow[t];
        for (int i = dq; i < r4; i++) lcsr[st + i] = 1024;
    }

    /* wait for all 4 quarters' dis */
    if (t == 0) {
        while (__hip_atomic_load(arr1 + g, __ATOMIC_RELAXED, __HIP_MEMORY_SCOPE_AGENT) < 4) {}
        (void)__hip_atomic_load(arr1 + g, __ATOMIC_ACQUIRE, __HIP_MEMORY_SCOPE_AGENT);
    }
    __syncthreads();

    float dis_t = disg[(g << 10) + t];
    int sw = t & 7;

    /* stage hs1 = dis * xw for ALL 1024 nodes, swizzled */
    #pragma unroll
    for (int o4 = 0; o4 < 8; o4++)
        hsL4[t * 8 + (o4 ^ sw)] = make_float4(xw[4*o4] * dis_t, xw[4*o4+1] * dis_t,
                                              xw[4*o4+2] * dis_t, xw[4*o4+3] * dis_t);
    __syncthreads();

    /* layer-1 gather for own 256 nodes, 8 lanes/node; h1 -> global f32 */
    int q = t & 7, grp = t >> 3;
    #pragma unroll
    for (int pass = 0; pass < 2; pass++) {
        int lq = pass * 128 + grp;
        int ln = part * 256 + lq;
        int d = hist[lq];
        float dn = rsqrtf((float)(d + 1));
        int st = lrow[lq];
        float4 acc = hsL4[ln * 8 + (q ^ (ln & 7))];
        const ushort4* c4 = (const ushort4*)(lcsr + st);
        int d4 = (d + 3) >> 2;
        for (int i = 0; i < d4; i++) {
            ushort4 ss = c4[i];
            float4 v0 = hsL4[ss.x * 8 + (q ^ (ss.x & 7))];
            float4 v1 = hsL4[ss.y * 8 + (q ^ (ss.y & 7))];
            float4 v2 = hsL4[ss.z * 8 + (q ^ (ss.z & 7))];
            float4 v3 = hsL4[ss.w * 8 + (q ^ (ss.w & 7))];
            acc.x += (v0.x + v1.x) + (v2.x + v3.x);
            acc.y += (v0.y + v1.y) + (v2.y + v3.y);
            acc.z += (v0.z + v1.z) + (v2.z + v3.z);
            acc.w += (v0.w + v1.w) + (v2.w + v3.w);
        }
        float4 bb = ((const float4*)b1)[q];
        float4 r;
        r.x = ftanh(dn * acc.x + bb.x);
        r.y = ftanh(dn * acc.y + bb.y);
        r.z = ftanh(dn * acc.z + bb.z);
        r.w = ftanh(dn * acc.w + bb.w);
        ((float4*)h1g)[((size_t)(g << 10) + ln) * 8 + q] = r;
    }
    __syncthreads();  /* drain h1g stores */
    if (t == 0) {
        __hip_atomic_fetch_add(arr2 + g, 1, __ATOMIC_RELEASE, __HIP_MEMORY_SCOPE_AGENT);
        while (__hip_atomic_load(arr2 + g, __ATOMIC_RELAXED, __HIP_MEMORY_SCOPE_AGENT) < 4) {}
        (void)__hip_atomic_load(arr2 + g, __ATOMIC_ACQUIRE, __HIP_MEMORY_SCOPE_AGENT);
    }
    __syncthreads();

    /* read full h1 row for node t, stage hs2 = dis * (h1 @ W2^T) */
    float r2[32];
    {
        const float4* h4 = (const float4*)(h1g + ((size_t)(g << 10) + t) * 32);
        #pragma unroll
        for (int k = 0; k < 8; k++) {
            float4 v = h4[k];
            r2[4*k] = v.x; r2[4*k+1] = v.y; r2[4*k+2] = v.z; r2[4*k+3] = v.w;
        }
    }
    #pragma unroll
    for (int o4 = 0; o4 < 8; o4++) {
        float r[4];
        #pragma unroll
        for (int j = 0; j < 4; j++) {
            int o = o4 * 4 + j;
            float s = 0.f;
            #pragma unroll
            for (int k = 0; k < 32; k++) s += r2[k] * W2[o * 32 + k];
            r[j] = s * dis_t;
        }
        hsL4[t * 8 + (o4 ^ sw)] = make_float4(r[0], r[1], r[2], r[3]);
    }
    __syncthreads();

    /* layer-2 gather (same LDS CSR), keep results in registers */
    float4 racc[2];
    #pragma unroll
    for (int pass = 0; pass < 2; pass++) {
        int lq = pass * 128 + grp;
        int ln = part * 256 + lq;
        int d = hist[lq];
        float dn = rsqrtf((float)(d + 1));
        int st = lrow[lq];
        float4 acc = hsL4[ln * 8 + (q ^ (ln & 7))];
        const ushort4* c4 = (const ushort4*)(lcsr + st);
        int d4 = (d + 3) >> 2;
        for (int i = 0; i < d4; i++) {
            ushort4 ss = c4[i];
            float4 v0 = hsL4[ss.x * 8 + (q ^ (ss.x & 7))];
            float4 v1 = hsL4[ss.y * 8 + (q ^ (ss.y & 7))];
            float4 v2 = hsL4[ss.z * 8 + (q ^ (ss.z & 7))];
            float4 v3 = hsL4[ss.w * 8 + (q ^ (ss.w & 7))];
            acc.x += (v0.x + v1.x) + (v2.x + v3.x);
            acc.y += (v0.y + v1.y) + (v2.y + v3.y);
            acc.z += (v0.z + v1.z) + (v2.z + v3.z);
            acc.w += (v0.w + v1.w) + (v2.w + v3.w);
        }
        float4 bb = ((const float4*)b2)[q];
        float4 r;
        r.x = ftanh(dn * acc.x + bb.x);
        r.y = ftanh(dn * acc.y + bb.y);
        r.z = ftanh(dn * acc.z + bb.z);
        r.w = ftanh(dn * acc.w + bb.w);
        racc[pass] = r;
    }

    /* h2 -> LOCAL LDS rows 0..255, then h3 = tanh(h2 @ Wl^T + bl), pool */
    __syncthreads();
    #pragma unroll
    for (int pass = 0; pass < 2; pass++) {
        int lnn = pass * 128 + grp;
        hsL4[lnn * 8 + (q ^ (lnn & 7))] = racc[pass];
    }
    __syncthreads();
    int o = t & 31, seg = t >> 5;
    float ps = 0.f;
    {
        float wlr[32];
        #pragma unroll
        for (int k = 0; k < 32; k++) wlr[k] = Wl[o * 32 + k];
        float blv = bl[o];
        #pragma unroll
        for (int j = 0; j < 8; j++) {
            int nl = seg * 8 + j;
            int swn = nl & 7;
            float s = blv;
            #pragma unroll
            for (int k = 0; k < 32; k++) {
                float h2v = hsL[nl * 32 + ((((k >> 2) ^ swn) << 2) | (k & 3))];
                s += h2v * wlr[k];
            }
            ps += ftanh(s);
        }
    }
    float* psum = hsL + 8192;   /* rows 256-287: no overlap with rows 0-255 reads */
    psum[t] = ps;
    __syncthreads();
    if (t < 32) {
        float tot = 0.f;
        for (int s2 = 0; s2 < 32; s2++) tot += psum[s2 * 32 + t];
        pooled4[(g * 4 + part) * 32 + t] = tot;
    }
    __syncthreads();   /* drain pooled4 stores */
    if (t == 0)
        __hip_atomic_fetch_add(arr3 + g, 1, __ATOMIC_RELEASE, __HIP_MEMORY_SCOPE_AGENT);

    /* part-0 block runs the per-graph MLP tail (R7-proven) */
    if (part == 0) {
        if (t == 0) {
            while (__hip_atomic_load(arr3 + g, __ATOMIC_RELAXED, __HIP_MEMORY_SCOPE_AGENT) < 4) {}
            (void)__hip_atomic_load(arr3 + g, __ATOMIC_ACQUIRE, __HIP_MEMORY_SCOPE_AGENT);
        }
        __syncthreads();
        if (t < 32) {
            int j = t;
            float p = pooled4[(g * 4 + 0) * 32 + j] + pooled4[(g * 4 + 1) * 32 + j]
                    + pooled4[(g * 4 + 2) * 32 + j] + pooled4[(g * 4 + 3) * 32 + j];
            float h1v = bp[j];
            #pragma unroll
            for (int k = 0; k < 32; k++) h1v += Wp[j * 32 + k] * __shfl(p, k, 32);
            float s0 = share[g * 64 + j];
            float s1 = share[g * 64 + 32 + j];
            float t1 = Vb1[j];
            #pragma unroll
            for (int k = 0; k < 32; k++) {
                t1 += Vw1[j * 64 + k] * __shfl(s0, k, 32);
                t1 += Vw1[j * 64 + 32 + k] * __shfl(s1, k, 32);
            }
            t1 = tanhf(t1);
            float t2 = Vb2[j];
            #pragma unroll
            for (int k = 0; k < 32; k++) t2 += Vw2[j * 32 + k] * __shfl(t1, k, 32);
            t2 = tanhf(t2);
            float h2v = Vb3[j];
            #pragma unroll
            for (int k = 0; k < 32; k++) h2v += Vw3[j * 32 + k] * __shfl(t2, k, 32);
            float z = Cb1[j];
            #pragma unroll
            for (int k = 0; k < 32; k++) {
                z += Cw1[j * 64 + k] * __shfl(h1v, k, 32);
                z += Cw1[j * 64 + 32 + k] * __shfl(h2v, k, 32);
            }
            z = tanhf(z);
            float v = Cw2[j] * z;
            v += __shfl_down(v, 16, 32); v += __shfl_down(v, 8, 32);
            v += __shfl_down(v, 4, 32);  v += __shfl_down(v, 2, 32);
            v += __shfl_down(v, 1, 32);
            if (j == 0) out[g] = v + Cb2[0];
        }
    }
}

extern "C" void kernel_launch(void* const* d_in, const int* in_sizes, int n_in,
                              void* d_out, int out_size, void* d_ws, size_t ws_size,
                              hipStream_t stream) {
    const float* x     = (const float*)d_in[0];
    const int*   ei    = (const int*)d_in[1];
    const float* share = (const float*)d_in[3];
    const float* W1 = (const float*)d_in[4];  const float* b1 = (const float*)d_in[5];
    const float* W2 = (const float*)d_in[6];  const float* b2 = (const float*)d_in[7];
    const float* Wl = (const float*)d_in[8];  const float* bl = (const float*)d_in[9];
    const float* Wp = (const float*)d_in[10]; const float* bp = (const float*)d_in[11];
    const float* Vw1 = (const float*)d_in[12]; const float* Vb1 = (const float*)d_in[13];
    const float* Vw2 = (const float*)d_in[14]; const float* Vb2 = (const float*)d_in[15];
    const float* Vw3 = (const float*)d_in[16]; const float* Vb3 = (const float*)d_in[17];
    const float* Cw1 = (const float*)d_in[18]; const float* Cb1 = (const float*)d_in[19];
    const float* Cw2 = (const float*)d_in[20]; const float* Cb2 = (const float*)d_in[21];

    char* ws = (char*)d_ws;
    int*          gfill   = (int*)(ws + OFF_GFILL);
    int*          arr1    = (int*)(ws + OFF_ARR1);
    int*          arr2    = (int*)(ws + OFF_ARR2);
    int*          arr3    = (int*)(ws + OFF_ARR3);
    float*        pooled4 = (float*)(ws + OFF_POOL4);
    float*        disg    = (float*)(ws + OFF_DIS);
    float*        h1g     = (float*)(ws + OFF_H1G);
    unsigned int* ebuf    = (unsigned int*)(ws + OFF_EBUF);

    const int* srcp = ei;
    const int* dstp = ei + NEDGES;

    hipMemsetAsync(ws, 0, 2048, stream);  /* gfill + arr1/2/3 */

    k_bucket<<<256, 1024, 0, stream>>>(srcp, dstp, gfill, ebuf);
    k_gcn<<<256, 1024, 0, stream>>>(x, W1, b1, W2, b2, Wl, bl, Wp, bp,
                                    Vw1, Vb1, Vw2, Vb2, Vw3, Vb3,
                                    Cw1, Cb1, Cw2, Cb2, share,
                                    ebuf, gfill, disg, h1g,
                                    arr1, arr2, arr3, pooled4, (float*)d_out);
}

// Round 9
// 181.491 us; speedup vs baseline: 1.0163x; 1.0163x over previous
//
#include <hip/hip_runtime.h>
#include <math.h>

#define NNODES 65536
#define NEDGES 2097152
#define PGRAPH 1024
#define NGRAPH 64
#define CAPB   9216    /* per-(graph,quarter) bucket cap: mean 8192, sigma~90 -> +11 sigma */
#define CAPQ   9728    /* per-quarter CSR cap: mean 8192 + align-pad<=768 + 8.5 sigma      */

/* ws layout (bytes) — round-1 layout verbatim */
#define OFF_GFILL 0u          /* int[256]  per-bucket fill                 */
#define OFF_ARR   1024u       /* int[128]  arrive1[64], arrive2[64]        */
#define OFF_POOL4 1536u       /* float[256*32] partial pools -> 34304      */
#define OFF_DIS   34304u      /* float[65536] -> 296448                    */
#define OFF_EBUF  296448u     /* uint[256*CAPB] = 9437184 -> 9733632       */
#define OFF_H1G   9733632u    /* float[65536*32] = 8388608                 */

__device__ __forceinline__ float ftanh(float x) {
    float e = __expf(2.f * x);
    return 1.f - 2.f * __builtin_amdgcn_rcpf(e + 1.f);
}

/* ---- bucket edges by (graph, dst-quarter): 256 buckets; 1024 threads/block
   (16 waves/CU) for latency hiding. R5/R8-proven; same ebuf format as R1. ---- */
__global__ __launch_bounds__(1024) void k_bucket(
        const int* __restrict__ src, const int* __restrict__ dst,
        int* __restrict__ gfill, unsigned int* __restrict__ ebuf) {
    __shared__ unsigned int sorted[8192];
    __shared__ int hist[256], lexcl[256], gbase[256], lfill[256];
    __shared__ int wsum[4];
    int t = threadIdx.x;
    int blk = blockIdx.x;
    int lane = t & 63, wid = t >> 6;

    if (t < 256) { hist[t] = 0; lfill[t] = 0; }
    __syncthreads();

    unsigned int pk[8];
    {
        const int4* s4p = (const int4*)(src + blk * 8192);
        const int4* d4p = (const int4*)(dst + blk * 8192);
        #pragma unroll
        for (int k = 0; k < 2; k++) {
            int4 s4 = s4p[k * 1024 + t];
            int4 d4 = d4p[k * 1024 + t];
            int ss[4] = { s4.x, s4.y, s4.z, s4.w };
            int dd[4] = { d4.x, d4.y, d4.z, d4.w };
            #pragma unroll
            for (int j = 0; j < 4; j++) {
                int gg = ss[j] >> 10;
                /* pack: src_local | dst_local<<10 | g<<20 ; bucket = pk>>18 */
                pk[k * 4 + j] = (unsigned int)((ss[j] & 1023) | ((dd[j] & 1023) << 10) | (gg << 20));
                atomicAdd(&hist[(gg << 2) | ((dd[j] >> 8) & 3)], 1);
            }
        }
    }
    __syncthreads();

    int hA = 0, xxA = 0;
    if (t < 256) {
        hA = hist[t];
        xxA = hA;
        #pragma unroll
        for (int off = 1; off < 64; off <<= 1) {
            int y = __shfl_up(xxA, off, 64);
            if (lane >= off) xxA += y;
        }
        if (lane == 63) wsum[wid] = xxA;
    }
    __syncthreads();
    if (t < 256) {
        int pre = 0;
        for (int w = 0; w < wid; w++) pre += wsum[w];
        lexcl[t] = pre + xxA - hA;
        gbase[t] = atomicAdd(&gfill[t], hA);
    }
    __syncthreads();

    #pragma unroll
    for (int k = 0; k < 8; k++) {
        int b = pk[k] >> 18;
        int pos = lexcl[b] + atomicAdd(&lfill[b], 1);
        sorted[pos] = pk[k];
    }
    __syncthreads();
    #pragma unroll
    for (int k = 0; k < 8; k++) {
        int i = k * 1024 + t;
        unsigned int p = sorted[i];
        int b = p >> 18;
        ebuf[(size_t)b * CAPB + gbase[b] + (i - lexcl[b])] = p;
    }
}

/* ---- fused GCN: round-1 body VERBATIM (58us, absmax 0). ---- */
__global__ __launch_bounds__(1024, 1) void k_gcn(
        const float* __restrict__ x,
        const float* __restrict__ W1, const float* __restrict__ b1,
        const float* __restrict__ W2, const float* __restrict__ b2,
        const float* __restrict__ Wl, const float* __restrict__ bl,
        const unsigned int* __restrict__ ebuf, const int* __restrict__ gfill,
        float* __restrict__ disg, float* __restrict__ h1g,
        int* __restrict__ arrive, float* __restrict__ pooled4) {
    __shared__ float hsL[1025 * 32];          /* 131200 B, row 1024 = zeros */
    __shared__ unsigned short lcsr[CAPQ];     /* 19456 B */
    __shared__ float WlL[32 * 33];            /* 4224 B  */
    __shared__ int hist[256], lrow[256], lfill[256];
    __shared__ int wsum[4];
    float4* hsL4 = (float4*)hsL;

    int t = threadIdx.x;
    int g = blockIdx.x & 63, part = blockIdx.x >> 6;
    int bkt = (g << 2) | part;
    int cnt = gfill[bkt];
    const unsigned int* eb = ebuf + (size_t)bkt * CAPB;

    /* preload x row early so its latency overlaps the edge scan */
    float inr[16];
    {
        const float4* in4 = (const float4*)(x + ((size_t)(g << 10) + t) * 16);
        #pragma unroll
        for (int k = 0; k < 4; k++) {
            float4 v = in4[k];
            inr[4*k] = v.x; inr[4*k+1] = v.y; inr[4*k+2] = v.z; inr[4*k+3] = v.w;
        }
    }

    if (t < 256) hist[t] = 0;
    WlL[(t >> 5) * 33 + (t & 31)] = Wl[t];
    if (t < 32) hsL[1024 * 32 + t] = 0.f;     /* zero row for CSR padding */
    __syncthreads();

    /* pass 1: degree hist over own bucket (~8K edges) */
    for (int i = t; i < cnt; i += 1024) atomicAdd(&hist[(eb[i] >> 10) & 255], 1);
    __syncthreads();

    /* publish this quarter's dis, release flag 1 */
    int dq = 0, r4 = 0;
    if (t < 256) {
        dq = hist[t]; r4 = (dq + 3) & ~3;
        disg[(g << 10) + part * 256 + t] = rsqrtf((float)(dq + 1));
    }
    __syncthreads();  /* drains vmem: disg stores are in L2 before the release */
    if (t == 0)
        __hip_atomic_fetch_add(arrive + g, 1, __ATOMIC_RELEASE, __HIP_MEMORY_SCOPE_AGENT);

    /* 256-wide exclusive scan of 4-aligned degrees -> CSR row starts */
    int lane = t & 63, wid = t >> 6;
    int xx = r4;
    #pragma unroll
    for (int off = 1; off < 64; off <<= 1) {
        int y = __shfl_up(xx, off, 64);
        if (lane >= off) xx += y;
    }
    if (t < 256 && lane == 63) wsum[wid] = xx;
    __syncthreads();
    if (t < 256) {
        int pre = 0;
        for (int w = 0; w < wid; w++) pre += wsum[w];
        lrow[t] = pre + xx - r4;
        lfill[t] = 0;
    }
    __syncthreads();

    /* pass 2: scatter own bucket into LDS CSR; pad rows to x4 with zero-row idx */
    for (int i = t; i < cnt; i += 1024) {
        unsigned int v = eb[i];
        int dl = (v >> 10) & 255;
        int pos = lrow[dl] + atomicAdd(&lfill[dl], 1);
        lcsr[pos] = (unsigned short)(v & 1023);
    }
    if (t < 256) {
        int st = lrow[t];
        for (int i = dq; i < r4; i++) lcsr[st + i] = 1024;
    }

    /* wait for all 4 quarters' dis */
    if (t == 0) {
        while (__hip_atomic_load(arrive + g, __ATOMIC_RELAXED, __HIP_MEMORY_SCOPE_AGENT) < 4) {}
        (void)__hip_atomic_load(arrive + g, __ATOMIC_ACQUIRE, __HIP_MEMORY_SCOPE_AGENT);
    }
    __syncthreads();

    float dis_t = disg[(g << 10) + t];
    int sw = t & 7;

    /* stage hs1 = dis * (x @ W1^T) for ALL 1024 nodes, swizzled */
    #pragma unroll
    for (int o4 = 0; o4 < 8; o4++) {
        float r[4];
        #pragma unroll
        for (int j = 0; j < 4; j++) {
            int o = o4 * 4 + j;
            float s = 0.f;
            #pragma unroll
            for (int k = 0; k < 16; k++) s += inr[k] * W1[o * 16 + k];
            r[j] = s * dis_t;
        }
        hsL4[t * 8 + (o4 ^ sw)] = make_float4(r[0], r[1], r[2], r[3]);
    }
    __syncthreads();

    /* layer-1 gather for own 256 nodes, 8 lanes/node; h1 -> global f32 */
    int q = t & 7, grp = t >> 3;
    #pragma unroll
    for (int pass = 0; pass < 2; pass++) {
        int lq = pass * 128 + grp;
        int ln = part * 256 + lq;
        int d = hist[lq];
        float dn = rsqrtf((float)(d + 1));
        int st = lrow[lq];
        float4 acc = hsL4[ln * 8 + (q ^ (ln & 7))];
        const ushort4* c4 = (const ushort4*)(lcsr + st);
        int d4 = (d + 3) >> 2;
        for (int i = 0; i < d4; i++) {
            ushort4 ss = c4[i];
            float4 v0 = hsL4[ss.x * 8 + (q ^ (ss.x & 7))];
            float4 v1 = hsL4[ss.y * 8 + (q ^ (ss.y & 7))];
            float4 v2 = hsL4[ss.z * 8 + (q ^ (ss.z & 7))];
            float4 v3 = hsL4[ss.w * 8 + (q ^ (ss.w & 7))];
            acc.x += (v0.x + v1.x) + (v2.x + v3.x);
            acc.y += (v0.y + v1.y) + (v2.y + v3.y);
            acc.z += (v0.z + v1.z) + (v2.z + v3.z);
            acc.w += (v0.w + v1.w) + (v2.w + v3.w);
        }
        float4 bb = ((const float4*)b1)[q];
        float4 r;
        r.x = ftanh(dn * acc.x + bb.x);
        r.y = ftanh(dn * acc.y + bb.y);
        r.z = ftanh(dn * acc.z + bb.z);
        r.w = ftanh(dn * acc.w + bb.w);
        ((float4*)h1g)[((size_t)(g << 10) + ln) * 8 + q] = r;
    }
    __syncthreads();  /* drain h1g stores */
    if (t == 0) {
        __hip_atomic_fetch_add(arrive + 64 + g, 1, __ATOMIC_RELEASE, __HIP_MEMORY_SCOPE_AGENT);
        while (__hip_atomic_load(arrive + 64 + g, __ATOMIC_RELAXED, __HIP_MEMORY_SCOPE_AGENT) < 4) {}
        (void)__hip_atomic_load(arrive + 64 + g, __ATOMIC_ACQUIRE, __HIP_MEMORY_SCOPE_AGENT);
    }
    __syncthreads();

    /* read full h1 row for node t (L2-local), stage hs2 = dis * (h1 @ W2^T) */
    float r2[32];
    {
        const float4* h4 = (const float4*)(h1g + ((size_t)(g << 10) + t) * 32);
        #pragma unroll
        for (int k = 0; k < 8; k++) {
            float4 v = h4[k];
            r2[4*k] = v.x; r2[4*k+1] = v.y; r2[4*k+2] = v.z; r2[4*k+3] = v.w;
        }
    }
    #pragma unroll
    for (int o4 = 0; o4 < 8; o4++) {
        float r[4];
        #pragma unroll
        for (int j = 0; j < 4; j++) {
            int o = o4 * 4 + j;
            float s = 0.f;
            #pragma unroll
            for (int k = 0; k < 32; k++) s += r2[k] * W2[o * 32 + k];
            r[j] = s * dis_t;
        }
        hsL4[t * 8 + (o4 ^ sw)] = make_float4(r[0], r[1], r[2], r[3]);
    }
    __syncthreads();

    /* layer-2 gather (same LDS CSR), keep results in registers */
    float4 racc[2];
    #pragma unroll
    for (int pass = 0; pass < 2; pass++) {
        int lq = pass * 128 + grp;
        int ln = part * 256 + lq;
        int d = hist[lq];
        float dn = rsqrtf((float)(d + 1));
        int st = lrow[lq];
        float4 acc = hsL4[ln * 8 + (q ^ (ln & 7))];
        const ushort4* c4 = (const ushort4*)(lcsr + st);
        int d4 = (d + 3) >> 2;
        for (int i = 0; i < d4; i++) {
            ushort4 ss = c4[i];
            float4 v0 = hsL4[ss.x * 8 + (q ^ (ss.x & 7))];
            float4 v1 = hsL4[ss.y * 8 + (q ^ (ss.y & 7))];
            float4 v2 = hsL4[ss.z * 8 + (q ^ (ss.z & 7))];
            float4 v3 = hsL4[ss.w * 8 + (q ^ (ss.w & 7))];
            acc.x += (v0.x + v1.x) + (v2.x + v3.x);
            acc.y += (v0.y + v1.y) + (v2.y + v3.y);
            acc.z += (v0.z + v1.z) + (v2.z + v3.z);
            acc.w += (v0.w + v1.w) + (v2.w + v3.w);
        }
        float4 bb = ((const float4*)b2)[q];
        float4 r;
        r.x = ftanh(dn * acc.x + bb.x);
        r.y = ftanh(dn * acc.y + bb.y);
        r.z = ftanh(dn * acc.z + bb.z);
        r.w = ftanh(dn * acc.w + bb.w);
        racc[pass] = r;
    }

    /* h3 = tanh(h2 @ Wl^T + bl), pool this block's 256 nodes */
    __syncthreads();
    #pragma unroll
    for (int pass = 0; pass < 2; pass++) {
        int lnn = pass * 128 + grp;
        hsL4[lnn * 8 + (q ^ (lnn & 7))] = racc[pass];
    }
    __syncthreads();
    int o = t & 31, seg = t >> 5;
    float ps = 0.f;
    #pragma unroll
    for (int j = 0; j < 8; j++) {
        int nl = seg * 8 + j;
        int swn = nl & 7;
        float s = bl[o];
        #pragma unroll
        for (int k = 0; k < 32; k++) {
            float h2v = hsL[nl * 32 + ((((k >> 2) ^ swn) << 2) | (k & 3))];
            s += h2v * WlL[o * 33 + k];
        }
        ps += ftanh(s);
    }
    float* psum = hsL + 8192;
    psum[t] = ps;
    __syncthreads();
    if (t < 32) {
        float tot = 0.f;
        for (int s = 0; s < 32; s++) tot += psum[s * 32 + t];
        pooled4[(g * 4 + part) * 32 + t] = tot;
    }
}

/* whole MLP tail: 64 graphs x 32 lanes (round-1 verbatim) */
__global__ void k_final(const float* __restrict__ pooled4, const float* __restrict__ share,
                        const float* __restrict__ Wp,  const float* __restrict__ bp,
                        const float* __restrict__ Vw1, const float* __restrict__ Vb1,
                        const float* __restrict__ Vw2, const float* __restrict__ Vb2,
                        const float* __restrict__ Vw3, const float* __restrict__ Vb3,
                        const float* __restrict__ Cw1, const float* __restrict__ Cb1,
                        const float* __restrict__ Cw2, const float* __restrict__ Cb2,
                        float* __restrict__ out) {
    int id = blockIdx.x * 256 + threadIdx.x;  /* 0..2047 */
    int b = id >> 5;
    int j = id & 31;
    float p = pooled4[(b * 4 + 0) * 32 + j] + pooled4[(b * 4 + 1) * 32 + j]
            + pooled4[(b * 4 + 2) * 32 + j] + pooled4[(b * 4 + 3) * 32 + j];
    float h1v = bp[j];
    #pragma unroll
    for (int k = 0; k < 32; k++) h1v += Wp[j * 32 + k] * __shfl(p, k, 32);
    float s0 = share[b * 64 + j];
    float s1 = share[b * 64 + 32 + j];
    float t1 = Vb1[j];
    #pragma unroll
    for (int k = 0; k < 32; k++) {
        t1 += Vw1[j * 64 + k] * __shfl(s0, k, 32);
        t1 += Vw1[j * 64 + 32 + k] * __shfl(s1, k, 32);
    }
    t1 = tanhf(t1);
    float t2 = Vb2[j];
    #pragma unroll
    for (int k = 0; k < 32; k++) t2 += Vw2[j * 32 + k] * __shfl(t1, k, 32);
    t2 = tanhf(t2);
    float h2v = Vb3[j];
    #pragma unroll
    for (int k = 0; k < 32; k++) h2v += Vw3[j * 32 + k] * __shfl(t2, k, 32);
    float z = Cb1[j];
    #pragma unroll
    for (int k = 0; k < 32; k++) {
        z += Cw1[j * 64 + k] * __shfl(h1v, k, 32);
        z += Cw1[j * 64 + 32 + k] * __shfl(h2v, k, 32);
    }
    z = tanhf(z);
    float v = Cw2[j] * z;
    v += __shfl_down(v, 16, 32); v += __shfl_down(v, 8, 32);
    v += __shfl_down(v, 4, 32);  v += __shfl_down(v, 2, 32);
    v += __shfl_down(v, 1, 32);
    if (j == 0) out[b] = v + Cb2[0];
}

extern "C" void kernel_launch(void* const* d_in, const int* in_sizes, int n_in,
                              void* d_out, int out_size, void* d_ws, size_t ws_size,
                              hipStream_t stream) {
    const float* x     = (const float*)d_in[0];
    const int*   ei    = (const int*)d_in[1];
    const float* share = (const float*)d_in[3];
    const float* W1 = (const float*)d_in[4];  const float* b1 = (const float*)d_in[5];
    const float* W2 = (const float*)d_in[6];  const float* b2 = (const float*)d_in[7];
    const float* Wl = (const float*)d_in[8];  const float* bl = (const float*)d_in[9];
    const float* Wp = (const float*)d_in[10]; const float* bp = (const float*)d_in[11];
    const float* Vw1 = (const float*)d_in[12]; const float* Vb1 = (const float*)d_in[13];
    const float* Vw2 = (const float*)d_in[14]; const float* Vb2 = (const float*)d_in[15];
    const float* Vw3 = (const float*)d_in[16]; const float* Vb3 = (const float*)d_in[17];
    const float* Cw1 = (const float*)d_in[18]; const float* Cb1 = (const float*)d_in[19];
    const float* Cw2 = (const float*)d_in[20]; const float* Cb2 = (const float*)d_in[21];

    char* ws = (char*)d_ws;
    int*          gfill   = (int*)(ws + OFF_GFILL);
    int*          arrive  = (int*)(ws + OFF_ARR);
    float*        pooled4 = (float*)(ws + OFF_POOL4);
    float*        disg    = (float*)(ws + OFF_DIS);
    unsigned int* ebuf    = (unsigned int*)(ws + OFF_EBUF);
    float*        h1g     = (float*)(ws + OFF_H1G);

    const int* srcp = ei;
    const int* dstp = ei + NEDGES;

    hipMemsetAsync(ws, 0, 1536, stream);  /* gfill[256] + arrive[128] */

    k_bucket<<<256, 1024, 0, stream>>>(srcp, dstp, gfill, ebuf);
    k_gcn<<<256, 1024, 0, stream>>>(x, W1, b1, W2, b2, Wl, bl,
                                    ebuf, gfill, disg, h1g, arrive, pooled4);
    k_final<<<8, 256, 0, stream>>>(pooled4, share, Wp, bp, Vw1, Vb1, Vw2, Vb2,
                                   Vw3, Vb3, Cw1, Cb1, Cw2, Cb2, (float*)d_out);
}

// Round 11
// 174.900 us; speedup vs baseline: 1.0546x; 1.0377x over previous
//
#include <hip/hip_runtime.h>
#include <math.h>

#define NNODES 65536
#define NEDGES 2097152
#define PGRAPH 1024
#define NGRAPH 64
#define CAPB   9216    /* per-(graph,quarter) bucket cap: mean 8192, sigma~90 -> +11 sigma */
#define CAPQ   9728    /* per-quarter CSR cap: mean 8192 + align-pad<=768 + 8.5 sigma      */

/* ws layout (bytes) */
#define OFF_GFILL 0u          /* int[256]  per-bucket fill                     */
#define OFF_ARR   1024u       /* int[192]  arrive1[64], arrive2[64], arrive3[64] */
#define OFF_POOL4 2048u       /* float[256*32] partial pools -> 34816          */
#define OFF_DIS   34816u      /* float[65536] -> 296960                        */
#define OFF_EBUF  296960u     /* uint[256*CAPB] = 9437184 -> 9734144           */
#define OFF_H1G   9734144u    /* float[65536*32] = 8388608                     */

__device__ __forceinline__ float ftanh(float x) {
    float e = __expf(2.f * x);
    return 1.f - 2.f * __builtin_amdgcn_rcpf(e + 1.f);
}

/* ---- bucket edges by (graph, dst-quarter): 256 buckets; 1024 threads/block
   (16 waves/CU). R9 verbatim. ---- */
__global__ __launch_bounds__(1024) void k_bucket(
        const int* __restrict__ src, const int* __restrict__ dst,
        int* __restrict__ gfill, unsigned int* __restrict__ ebuf) {
    __shared__ unsigned int sorted[8192];
    __shared__ int hist[256], lexcl[256], gbase[256], lfill[256];
    __shared__ int wsum[4];
    int t = threadIdx.x;
    int blk = blockIdx.x;
    int lane = t & 63, wid = t >> 6;

    if (t < 256) { hist[t] = 0; lfill[t] = 0; }
    __syncthreads();

    unsigned int pk[8];
    {
        const int4* s4p = (const int4*)(src + blk * 8192);
        const int4* d4p = (const int4*)(dst + blk * 8192);
        #pragma unroll
        for (int k = 0; k < 2; k++) {
            int4 s4 = s4p[k * 1024 + t];
            int4 d4 = d4p[k * 1024 + t];
            int ss[4] = { s4.x, s4.y, s4.z, s4.w };
            int dd[4] = { d4.x, d4.y, d4.z, d4.w };
            #pragma unroll
            for (int j = 0; j < 4; j++) {
                int gg = ss[j] >> 10;
                /* pack: src_local | dst_local<<10 | g<<20 ; bucket = pk>>18 */
                pk[k * 4 + j] = (unsigned int)((ss[j] & 1023) | ((dd[j] & 1023) << 10) | (gg << 20));
                atomicAdd(&hist[(gg << 2) | ((dd[j] >> 8) & 3)], 1);
            }
        }
    }
    __syncthreads();

    int hA = 0, xxA = 0;
    if (t < 256) {
        hA = hist[t];
        xxA = hA;
        #pragma unroll
        for (int off = 1; off < 64; off <<= 1) {
            int y = __shfl_up(xxA, off, 64);
            if (lane >= off) xxA += y;
        }
        if (lane == 63) wsum[wid] = xxA;
    }
    __syncthreads();
    if (t < 256) {
        int pre = 0;
        for (int w = 0; w < wid; w++) pre += wsum[w];
        lexcl[t] = pre + xxA - hA;
        gbase[t] = atomicAdd(&gfill[t], hA);
    }
    __syncthreads();

    #pragma unroll
    for (int k = 0; k < 8; k++) {
        int b = pk[k] >> 18;
        int pos = lexcl[b] + atomicAdd(&lfill[b], 1);
        sorted[pos] = pk[k];
    }
    __syncthreads();
    #pragma unroll
    for (int k = 0; k < 8; k++) {
        int i = k * 1024 + t;
        unsigned int p = sorted[i];
        int b = p >> 18;
        ebuf[(size_t)b * CAPB + gbase[b] + (i - lexcl[b])] = p;
    }
}

/* ---- fused GCN: round-1 body VERBATIM (56.5us, absmax 0) + folded MLP
   tail (arr3 flag; part-0 block). 256 blocks x 1024 thr, 1 block/CU. ---- */
__global__ __launch_bounds__(1024, 1) void k_gcn(
        const float* __restrict__ x,
        const float* __restrict__ W1, const float* __restrict__ b1,
        const float* __restrict__ W2, const float* __restrict__ b2,
        const float* __restrict__ Wl, const float* __restrict__ bl,
        const float* __restrict__ Wp, const float* __restrict__ bp,
        const float* __restrict__ Vw1, const float* __restrict__ Vb1,
        const float* __restrict__ Vw2, const float* __restrict__ Vb2,
        const float* __restrict__ Vw3, const float* __restrict__ Vb3,
        const float* __restrict__ Cw1, const float* __restrict__ Cb1,
        const float* __restrict__ Cw2, const float* __restrict__ Cb2,
        const float* __restrict__ share,
        const unsigned int* __restrict__ ebuf, const int* __restrict__ gfill,
        float* __restrict__ disg, float* __restrict__ h1g,
        int* __restrict__ arrive, float* __restrict__ pooled4,
        float* __restrict__ out) {
    __shared__ float hsL[1025 * 32];          /* 131200 B, row 1024 = zeros */
    __shared__ unsigned short lcsr[CAPQ];     /* 19456 B */
    __shared__ float WlL[32 * 33];            /* 4224 B  */
    __shared__ int hist[256], lrow[256], lfill[256];
    __shared__ int wsum[4];
    float4* hsL4 = (float4*)hsL;

    int t = threadIdx.x;
    int g = blockIdx.x & 63, part = blockIdx.x >> 6;
    int bkt = (g << 2) | part;
    int cnt = gfill[bkt];
    const unsigned int* eb = ebuf + (size_t)bkt * CAPB;

    /* preload x row early so its latency overlaps the edge scan */
    float inr[16];
    {
        const float4* in4 = (const float4*)(x + ((size_t)(g << 10) + t) * 16);
        #pragma unroll
        for (int k = 0; k < 4; k++) {
            float4 v = in4[k];
            inr[4*k] = v.x; inr[4*k+1] = v.y; inr[4*k+2] = v.z; inr[4*k+3] = v.w;
        }
    }

    if (t < 256) hist[t] = 0;
    WlL[(t >> 5) * 33 + (t & 31)] = Wl[t];
    if (t < 32) hsL[1024 * 32 + t] = 0.f;     /* zero row for CSR padding */
    __syncthreads();

    /* pass 1: degree hist over own bucket (~8K edges) */
    for (int i = t; i < cnt; i += 1024) atomicAdd(&hist[(eb[i] >> 10) & 255], 1);
    __syncthreads();

    /* publish this quarter's dis, release flag 1 */
    int dq = 0, r4 = 0;
    if (t < 256) {
        dq = hist[t]; r4 = (dq + 3) & ~3;
        disg[(g << 10) + part * 256 + t] = rsqrtf((float)(dq + 1));
    }
    __syncthreads();  /* drains vmem: disg stores are in L2 before the release */
    if (t == 0)
        __hip_atomic_fetch_add(arrive + g, 1, __ATOMIC_RELEASE, __HIP_MEMORY_SCOPE_AGENT);

    /* 256-wide exclusive scan of 4-aligned degrees -> CSR row starts */
    int lane = t & 63, wid = t >> 6;
    int xx = r4;
    #pragma unroll
    for (int off = 1; off < 64; off <<= 1) {
        int y = __shfl_up(xx, off, 64);
        if (lane >= off) xx += y;
    }
    if (t < 256 && lane == 63) wsum[wid] = xx;
    __syncthreads();
    if (t < 256) {
        int pre = 0;
        for (int w = 0; w < wid; w++) pre += wsum[w];
        lrow[t] = pre + xx - r4;
        lfill[t] = 0;
    }
    __syncthreads();

    /* pass 2: scatter own bucket into LDS CSR; pad rows to x4 with zero-row idx */
    for (int i = t; i < cnt; i += 1024) {
        unsigned int v = eb[i];
        int dl = (v >> 10) & 255;
        int pos = lrow[dl] + atomicAdd(&lfill[dl], 1);
        lcsr[pos] = (unsigned short)(v & 1023);
    }
    if (t < 256) {
        int st = lrow[t];
        for (int i = dq; i < r4; i++) lcsr[st + i] = 1024;
    }

    /* wait for all 4 quarters' dis */
    if (t == 0) {
        while (__hip_atomic_load(arrive + g, __ATOMIC_RELAXED, __HIP_MEMORY_SCOPE_AGENT) < 4) {}
        (void)__hip_atomic_load(arrive + g, __ATOMIC_ACQUIRE, __HIP_MEMORY_SCOPE_AGENT);
    }
    __syncthreads();

    float dis_t = disg[(g << 10) + t];
    int sw = t & 7;

    /* stage hs1 = dis * (x @ W1^T) for ALL 1024 nodes, swizzled */
    #pragma unroll
    for (int o4 = 0; o4 < 8; o4++) {
        float r[4];
        #pragma unroll
        for (int j = 0; j < 4; j++) {
            int o = o4 * 4 + j;
            float s = 0.f;
            #pragma unroll
            for (int k = 0; k < 16; k++) s += inr[k] * W1[o * 16 + k];
            r[j] = s * dis_t;
        }
        hsL4[t * 8 + (o4 ^ sw)] = make_float4(r[0], r[1], r[2], r[3]);
    }
    __syncthreads();

    /* layer-1 gather for own 256 nodes, 8 lanes/node; h1 -> global f32 */
    int q = t & 7, grp = t >> 3;
    #pragma unroll
    for (int pass = 0; pass < 2; pass++) {
        int lq = pass * 128 + grp;
        int ln = part * 256 + lq;
        int d = hist[lq];
        float dn = rsqrtf((float)(d + 1));
        int st = lrow[lq];
        float4 acc = hsL4[ln * 8 + (q ^ (ln & 7))];
        const ushort4* c4 = (const ushort4*)(lcsr + st);
        int d4 = (d + 3) >> 2;
        for (int i = 0; i < d4; i++) {
            ushort4 ss = c4[i];
            float4 v0 = hsL4[ss.x * 8 + (q ^ (ss.x & 7))];
            float4 v1 = hsL4[ss.y * 8 + (q ^ (ss.y & 7))];
            float4 v2 = hsL4[ss.z * 8 + (q ^ (ss.z & 7))];
            float4 v3 = hsL4[ss.w * 8 + (q ^ (ss.w & 7))];
            acc.x += (v0.x + v1.x) + (v2.x + v3.x);
            acc.y += (v0.y + v1.y) + (v2.y + v3.y);
            acc.z += (v0.z + v1.z) + (v2.z + v3.z);
            acc.w += (v0.w + v1.w) + (v2.w + v3.w);
        }
        float4 bb = ((const float4*)b1)[q];
        float4 r;
        r.x = ftanh(dn * acc.x + bb.x);
        r.y = ftanh(dn * acc.y + bb.y);
        r.z = ftanh(dn * acc.z + bb.z);
        r.w = ftanh(dn * acc.w + bb.w);
        ((float4*)h1g)[((size_t)(g << 10) + ln) * 8 + q] = r;
    }
    __syncthreads();  /* drain h1g stores */
    if (t == 0) {
        __hip_atomic_fetch_add(arrive + 64 + g, 1, __ATOMIC_RELEASE, __HIP_MEMORY_SCOPE_AGENT);
        while (__hip_atomic_load(arrive + 64 + g, __ATOMIC_RELAXED, __HIP_MEMORY_SCOPE_AGENT) < 4) {}
        (void)__hip_atomic_load(arrive + 64 + g, __ATOMIC_ACQUIRE, __HIP_MEMORY_SCOPE_AGENT);
    }
    __syncthreads();

    /* read full h1 row for node t (L2-local), stage hs2 = dis * (h1 @ W2^T) */
    float r2[32];
    {
        const float4* h4 = (const float4*)(h1g + ((size_t)(g << 10) + t) * 32);
        #pragma unroll
        for (int k = 0; k < 8; k++) {
            float4 v = h4[k];
            r2[4*k] = v.x; r2[4*k+1] = v.y; r2[4*k+2] = v.z; r2[4*k+3] = v.w;
        }
    }
    #pragma unroll
    for (int o4 = 0; o4 < 8; o4++) {
        float r[4];
        #pragma unroll
        for (int j = 0; j < 4; j++) {
            int o = o4 * 4 + j;
            float s = 0.f;
            #pragma unroll
            for (int k = 0; k < 32; k++) s += r2[k] * W2[o * 32 + k];
            r[j] = s * dis_t;
        }
        hsL4[t * 8 + (o4 ^ sw)] = make_float4(r[0], r[1], r[2], r[3]);
    }
    __syncthreads();

    /* layer-2 gather (same LDS CSR), keep results in registers */
    float4 racc[2];
    #pragma unroll
    for (int pass = 0; pass < 2; pass++) {
        int lq = pass * 128 + grp;
        int ln = part * 256 + lq;
        int d = hist[lq];
        float dn = rsqrtf((float)(d + 1));
        int st = lrow[lq];
        float4 acc = hsL4[ln * 8 + (q ^ (ln & 7))];
        const ushort4* c4 = (const ushort4*)(lcsr + st);
        int d4 = (d + 3) >> 2;
        for (int i = 0; i < d4; i++) {
            ushort4 ss = c4[i];
            float4 v0 = hsL4[ss.x * 8 + (q ^ (ss.x & 7))];
            float4 v1 = hsL4[ss.y * 8 + (q ^ (ss.y & 7))];
            float4 v2 = hsL4[ss.z * 8 + (q ^ (ss.z & 7))];
            float4 v3 = hsL4[ss.w * 8 + (q ^ (ss.w & 7))];
            acc.x += (v0.x + v1.x) + (v2.x + v3.x);
            acc.y += (v0.y + v1.y) + (v2.y + v3.y);
            acc.z += (v0.z + v1.z) + (v2.z + v3.z);
            acc.w += (v0.w + v1.w) + (v2.w + v3.w);
        }
        float4 bb = ((const float4*)b2)[q];
        float4 r;
        r.x = ftanh(dn * acc.x + bb.x);
        r.y = ftanh(dn * acc.y + bb.y);
        r.z = ftanh(dn * acc.z + bb.z);
        r.w = ftanh(dn * acc.w + bb.w);
        racc[pass] = r;
    }

    /* h3 = tanh(h2 @ Wl^T + bl), pool this block's 256 nodes */
    __syncthreads();
    #pragma unroll
    for (int pass = 0; pass < 2; pass++) {
        int lnn = pass * 128 + grp;
        hsL4[lnn * 8 + (q ^ (lnn & 7))] = racc[pass];
    }
    __syncthreads();
    int o = t & 31, seg = t >> 5;
    float ps = 0.f;
    #pragma unroll
    for (int j = 0; j < 8; j++) {
        int nl = seg * 8 + j;
        int swn = nl & 7;
        float s = bl[o];
        #pragma unroll
        for (int k = 0; k < 32; k++) {
            float h2v = hsL[nl * 32 + ((((k >> 2) ^ swn) << 2) | (k & 3))];
            s += h2v * WlL[o * 33 + k];
        }
        ps += ftanh(s);
    }
    float* psum = hsL + 8192;
    psum[t] = ps;
    __syncthreads();
    if (t < 32) {
        float tot = 0.f;
        for (int s = 0; s < 32; s++) tot += psum[s * 32 + t];
        pooled4[(g * 4 + part) * 32 + t] = tot;
    }
    __syncthreads();   /* drain pooled4 stores */
    if (t == 0)
        __hip_atomic_fetch_add(arrive + 128 + g, 1, __ATOMIC_RELEASE, __HIP_MEMORY_SCOPE_AGENT);

    /* part-0 block runs the per-graph MLP tail */
    if (part == 0) {
        if (t == 0) {
            while (__hip_atomic_load(arrive + 128 + g, __ATOMIC_RELAXED, __HIP_MEMORY_SCOPE_AGENT) < 4) {}
            (void)__hip_atomic_load(arrive + 128 + g, __ATOMIC_ACQUIRE, __HIP_MEMORY_SCOPE_AGENT);
        }
        __syncthreads();
        if (t < 32) {
            int j = t;
            float p = pooled4[(g * 4 + 0) * 32 + j] + pooled4[(g * 4 + 1) * 32 + j]
                    + pooled4[(g * 4 + 2) * 32 + j] + pooled4[(g * 4 + 3) * 32 + j];
            float h1v = bp[j];
            #pragma unroll
            for (int k = 0; k < 32; k++) h1v += Wp[j * 32 + k] * __shfl(p, k, 32);
            float s0 = share[g * 64 + j];
            float s1 = share[g * 64 + 32 + j];
            float t1 = Vb1[j];
            #pragma unroll
            for (int k = 0; k < 32; k++) {
                t1 += Vw1[j * 64 + k] * __shfl(s0, k, 32);
                t1 += Vw1[j * 64 + 32 + k] * __shfl(s1, k, 32);
            }
            t1 = tanhf(t1);
            float t2 = Vb2[j];
            #pragma unroll
            for (int k = 0; k < 32; k++) t2 += Vw2[j * 32 + k] * __shfl(t1, k, 32);
            t2 = tanhf(t2);
            float h2v = Vb3[j];
            #pragma unroll
            for (int k = 0; k < 32; k++) h2v += Vw3[j * 32 + k] * __shfl(t2, k, 32);
            float z = Cb1[j];
            #pragma unroll
            for (int k = 0; k < 32; k++) {
                z += Cw1[j * 64 + k] * __shfl(h1v, k, 32);
                z += Cw1[j * 64 + 32 + k] * __shfl(h2v, k, 32);
            }
            z = tanhf(z);
            float v = Cw2[j] * z;
            v += __shfl_down(v, 16, 32); v += __shfl_down(v, 8, 32);
            v += __shfl_down(v, 4, 32);  v += __shfl_down(v, 2, 32);
            v += __shfl_down(v, 1, 32);
            if (j == 0) out[g] = v + Cb2[0];
        }
    }
}

extern "C" void kernel_launch(void* const* d_in, const int* in_sizes, int n_in,
                              void* d_out, int out_size, void* d_ws, size_t ws_size,
                              hipStream_t stream) {
    const float* x     = (const float*)d_in[0];
    const int*   ei    = (const int*)d_in[1];
    const float* share = (const float*)d_in[3];
    const float* W1 = (const float*)d_in[4];  const float* b1 = (const float*)d_in[5];
    const float* W2 = (const float*)d_in[6];  const float* b2 = (const float*)d_in[7];
    const float* Wl = (const float*)d_in[8];  const float* bl = (const float*)d_in[9];
    const float* Wp = (const float*)d_in[10]; const float* bp = (const float*)d_in[11];
    const float* Vw1 = (const float*)d_in[12]; const float* Vb1 = (const float*)d_in[13];
    const float* Vw2 = (const float*)d_in[14]; const float* Vb2 = (const float*)d_in[15];
    const float* Vw3 = (const float*)d_in[16]; const float* Vb3 = (const float*)d_in[17];
    const float* Cw1 = (const float*)d_in[18]; const float* Cb1 = (const float*)d_in[19];
    const float* Cw2 = (const float*)d_in[20]; const float* Cb2 = (const float*)d_in[21];

    char* ws = (char*)d_ws;
    int*          gfill   = (int*)(ws + OFF_GFILL);
    int*          arrive  = (int*)(ws + OFF_ARR);
    float*        pooled4 = (float*)(ws + OFF_POOL4);
    float*        disg    = (float*)(ws + OFF_DIS);
    unsigned int* ebuf    = (unsigned int*)(ws + OFF_EBUF);
    float*        h1g     = (float*)(ws + OFF_H1G);

    const int* srcp = ei;
    const int* dstp = ei + NEDGES;

    hipMemsetAsync(ws, 0, 2048, stream);  /* gfill[256] + arrive[192] */

    k_bucket<<<256, 1024, 0, stream>>>(srcp, dstp, gfill, ebuf);
    k_gcn<<<256, 1024, 0, stream>>>(x, W1, b1, W2, b2, Wl, bl, Wp, bp,
                                    Vw1, Vb1, Vw2, Vb2, Vw3, Vb3,
                                    Cw1, Cb1, Cw2, Cb2, share,
                                    ebuf, gfill, disg, h1g, arrive, pooled4,
                                    (float*)d_out);
}